// Round 9
// baseline (489.867 us; speedup 1.0000x reference)
//
#include <hip/hip_runtime.h>

typedef unsigned int u32;
typedef unsigned short u16;
typedef __bf16 bf16x8 __attribute__((ext_vector_type(8)));
typedef float f32x4 __attribute__((ext_vector_type(4)));
typedef u32 u32x4 __attribute__((ext_vector_type(4)));
typedef u32 u32x2 __attribute__((ext_vector_type(2)));

#define NTOK 64
#define CDIM 256
#define NH 8

// ---- workspace layout (u16 units, after 16-byte flag header) ----
#define WS_HDR 8
#define BIAS_O (WS_HDR)             // [8][n 64][m 64] expanded bias (32768)
#define WQKV_O (BIAS_O + 32768)     // w_qkv bf16                    (196608)
#define BQKV_O (WQKV_O + 196608)    // b_qkv bf16                    (768)
#define WPRJ_O (BQKV_O + 768)       // w_proj bf16                   (65536)
#define BPRJ_O (WPRJ_O + 65536)     // b_proj bf16                   (256)

// ---- LDS: x tile [64][520B] = 33,280 B; reused as y tile after stage 1 ----
#define XROW 520
#define LDS_BYTES 33280

__device__ __forceinline__ float bf2f(u16 u) {
  union { u32 i; float f; } z; z.i = ((u32)u) << 16; return z.f;
}
__device__ __forceinline__ u16 f2bf(float f) {
  __bf16 h = (__bf16)f; return __builtin_bit_cast(u16, h);
}
__device__ __forceinline__ u32 pk2(float a, float b) {
  return (u32)f2bf(a) | ((u32)f2bf(b) << 16);
}
__device__ __forceinline__ float fetchf(const void* p, int idx, int isbf) {
  return isbf ? bf2f(((const u16*)p)[idx]) : ((const float*)p)[idx];
}

// Universal acc->frag repack (HW-verified rounds 6/7/8).
__device__ __forceinline__ bf16x8 frag_from(u32 p00, u32 p01, u32 p10, u32 p11,
                                            int s0, int s1, bool hi) {
  u32 A0 = (u32)__shfl((int)p00, s0, 64);
  u32 A1 = (u32)__shfl((int)p01, s0, 64);
  u32 B0 = (u32)__shfl((int)p10, s0, 64);
  u32 B1 = (u32)__shfl((int)p11, s0, 64);
  u32 C0 = (u32)__shfl((int)p00, s1, 64);
  u32 C1 = (u32)__shfl((int)p01, s1, 64);
  u32 D0 = (u32)__shfl((int)p10, s1, 64);
  u32 D1 = (u32)__shfl((int)p11, s1, 64);
  u32x4 f;
  f[0] = hi ? B0 : A0;  f[1] = hi ? B1 : A1;
  f[2] = hi ? D0 : C0;  f[3] = hi ? D1 : C1;
  return __builtin_bit_cast(bf16x8, f);
}

__global__ void detect_dtype(const u16* __restrict__ x, int* __restrict__ flag) {
  __shared__ int cnt;
  if (threadIdx.x == 0) cnt = 0;
  __syncthreads();
  int sane = 0;
  for (int i = threadIdx.x; i < 2048; i += 256) {
    u16 u = x[2 * i];
    int e = (u >> 7) & 0xFF;
    sane += (e == 0 || (e >= 90 && e <= 160)) ? 1 : 0;
  }
  atomicAdd(&cnt, sane);
  __syncthreads();
  if (threadIdx.x == 0) *flag = (cnt >= 1638) ? 1 : 0;
}

// bias expanded to [h][n][m]
__global__ void cvt_params(const void* __restrict__ wqkv, const void* __restrict__ bqkv,
                           const void* __restrict__ btab, const void* __restrict__ wprj,
                           const void* __restrict__ bprj, void* __restrict__ wsraw) {
  u16* ws = (u16*)wsraw;
  const int isbf = *(const int*)wsraw;
  int i = blockIdx.x * 256 + threadIdx.x;
  if (i < 32768) {
    int n = (i >> 6) & 63, m = i & 63, h = i >> 12;
    int r0 = (n >> 3) - (m >> 3) + 7, r1 = (n & 7) - (m & 7) + 7;
    ws[BIAS_O + i] = f2bf(fetchf(btab, (r0 * 15 + r1) * NH + h, isbf));
  } else if (i < 32768 + 196608) {
    int j = i - 32768;
    ws[WQKV_O + j] = f2bf(fetchf(wqkv, j, isbf));
  } else if (i < 32768 + 196608 + 768) {
    int j = i - (32768 + 196608);
    ws[BQKV_O + j] = f2bf(fetchf(bqkv, j, isbf));
  } else if (i < 32768 + 196608 + 768 + 65536) {
    int j = i - (32768 + 196608 + 768);
    ws[WPRJ_O + j] = f2bf(fetchf(wprj, j, isbf));
  } else if (i < 32768 + 196608 + 768 + 65536 + 256) {
    int j = i - (32768 + 196608 + 768 + 65536);
    ws[BPRJ_O + j] = f2bf(fetchf(bprj, j, isbf));
  }
}

// Strip-pair qkv tiles: xfs[2][8] preloaded; wf loaded once per tile, used for
// both strips. TILE_T2: transposed output (acc rows = channels, cols = tokens).
#define TILE_T2(PK, CHT, CHB, SCL, NT0) {                                             \
    bf16x8 wf[8];                                                                     \
    const u16* wrow = ws + WQKV_O + ((CHB) + c) * CDIM;                               \
    _Pragma("unroll")                                                                 \
    for (int ks = 0; ks < 8; ++ks) wf[ks] = *(const bf16x8*)(wrow + ks * 32 + g * 8); \
    f32x4 binit;                                                                      \
    { u32x2 bp = *(const u32x2*)(ws + BQKV_O + (CHB) + 4 * g);                        \
      binit[0] = bf2f((u16)(bp[0] & 0xffff)); binit[1] = bf2f((u16)(bp[0] >> 16));    \
      binit[2] = bf2f((u16)(bp[1] & 0xffff)); binit[3] = bf2f((u16)(bp[1] >> 16)); }  \
    _Pragma("unroll")                                                                 \
    for (int p = 0; p < 2; ++p) {                                                     \
      f32x4 acc = binit;                                                              \
      _Pragma("unroll")                                                               \
      for (int ks = 0; ks < 8; ++ks)                                                  \
        acc = __builtin_amdgcn_mfma_f32_16x16x32_bf16(wf[ks], xfs[p][ks], acc, 0, 0, 0); \
      PK[CHT][(NT0) + p][0] = pk2(acc[0] * (SCL), acc[1] * (SCL));                    \
      PK[CHT][(NT0) + p][1] = pk2(acc[2] * (SCL), acc[3] * (SCL));                    \
    } }

// TILE_N2: normal output (acc rows = tokens, col = channel) for v.
#define TILE_N2(PK, CHT, CHB, NT0) {                                                  \
    bf16x8 wf[8];                                                                     \
    const u16* wrow = ws + WQKV_O + ((CHB) + c) * CDIM;                               \
    _Pragma("unroll")                                                                 \
    for (int ks = 0; ks < 8; ++ks) wf[ks] = *(const bf16x8*)(wrow + ks * 32 + g * 8); \
    const float badd = bf2f(ws[BQKV_O + (CHB) + c]);                                  \
    _Pragma("unroll")                                                                 \
    for (int p = 0; p < 2; ++p) {                                                     \
      f32x4 acc = {badd, badd, badd, badd};                                           \
      _Pragma("unroll")                                                               \
      for (int ks = 0; ks < 8; ++ks)                                                  \
        acc = __builtin_amdgcn_mfma_f32_16x16x32_bf16(xfs[p][ks], wf[ks], acc, 0, 0, 0); \
      PK[CHT][(NT0) + p][0] = pk2(acc[0], acc[1]);                                    \
      PK[CHT][(NT0) + p][1] = pk2(acc[2], acc[3]);                                    \
    } }

// launch_bounds(512,2): VGPR cap 256 (spill-proof; the (512,4)=128 cap caused
// the round-6/7 scratch catastrophes).
__global__ __launch_bounds__(512, 2)
void win_attn_fused(const void* __restrict__ xraw, const void* __restrict__ wsraw,
                    float* __restrict__ out)
{
  __shared__ __align__(16) unsigned char lds[LDS_BYTES];
  const u16* ws  = (const u16*)wsraw;
  const int isbf = *(const int*)wsraw;
  const int b    = blockIdx.x;
  const int tid  = threadIdx.x;
  const int w    = tid >> 6;     // wave id = head id
  const int lane = tid & 63;
  const int c    = lane & 15;
  const int g    = lane >> 4;
  const float scale = 0.1767766952966369f;  // 32^-0.5

  // ---- stage 0: x[b] (64x256) -> LDS bf16 [64][520B]
  if (isbf) {
    const u32x4* gx = (const u32x4*)((const u16*)xraw + (size_t)b * (NTOK * CDIM));
#pragma unroll
    for (int i = 0; i < 4; ++i) {
      int q = tid + i * 512;
      int row = q >> 5, c8 = q & 31;
      *(u32x4*)(lds + row * XROW + c8 * 16) = gx[q];
    }
  } else {
    const f32x4* gx = (const f32x4*)((const float*)xraw + (size_t)b * (NTOK * CDIM));
#pragma unroll
    for (int i = 0; i < 8; ++i) {
      int q = tid + i * 512;
      int row = q >> 6, c4 = q & 63;
      f32x4 v = gx[q];
      u32x2 pkv;
      pkv[0] = pk2(v[0], v[1]);
      pkv[1] = pk2(v[2], v[3]);
      *(u32x2*)(lds + row * XROW + c4 * 8) = pkv;
    }
  }
  __syncthreads();   // B1

  const int s0 = c + 32 * (g & 1), s1 = s0 + 16;
  const bool hi = ((g >> 1) & 1) != 0;
  const int h = w;

  // ---- stage 1: per-head q,k (transposed) and v (normal), packed in registers.
  // nt-strip-pair outer: xfs hoisted once per pair -> xf LDS reads 192 -> 32/wave.
  u32 qpk[2][4][2], kpk[2][4][2];
  bf16x8 bvf[2][2];
  {
    u32 vpk[2][4][2];
#pragma unroll
    for (int np = 0; np < 2; ++np) {
      bf16x8 xfs[2][8];
#pragma unroll
      for (int p = 0; p < 2; ++p)
#pragma unroll
        for (int ks = 0; ks < 8; ++ks)
          xfs[p][ks] = *(const bf16x8*)(lds + (16 * (2 * np + p) + c) * XROW + ks * 64 + g * 16);
      TILE_T2(qpk, 0, 32 * w,             scale, 2 * np);
      TILE_T2(qpk, 1, 32 * w + 16,        scale, 2 * np);
      TILE_T2(kpk, 0, 256 + 32 * w,       1.0f,  2 * np);
      TILE_T2(kpk, 1, 256 + 32 * w + 16,  1.0f,  2 * np);
      TILE_N2(vpk, 0, 512 + 32 * w,       2 * np);
      TILE_N2(vpk, 1, 512 + 32 * w + 16,  2 * np);
    }
    // convert v -> B-frags NOW (frees vpk before the S^T/softmax phase)
#pragma unroll
    for (int dt = 0; dt < 2; ++dt)
#pragma unroll
      for (int k2 = 0; k2 < 2; ++k2)
        bvf[dt][k2] = frag_from(vpk[dt][2 * k2][0], vpk[dt][2 * k2][1],
                                vpk[dt][2 * k2 + 1][0], vpk[dt][2 * k2 + 1][1], s0, s1, hi);
  }
  __syncthreads();   // B2: x-LDS dead; region will hold y later

  // ---- S^T = k q^T + bias^T, softmax over m, P packed in regs (per-nt strips)
  bf16x8 bkf[4];
#pragma unroll
  for (int mt = 0; mt < 4; ++mt)
    bkf[mt] = frag_from(kpk[0][mt][0], kpk[0][mt][1], kpk[1][mt][0], kpk[1][mt][1], s0, s1, hi);

  u32 Ppk[4][4][2];
#pragma unroll
  for (int nt = 0; nt < 4; ++nt) {
    bf16x8 aqf = frag_from(qpk[0][nt][0], qpk[0][nt][1], qpk[1][nt][0], qpk[1][nt][1], s0, s1, hi);
    f32x4 st[4];
#pragma unroll
    for (int mt = 0; mt < 4; ++mt) {
      u32x2 bp = *(const u32x2*)(ws + BIAS_O + (h << 12) + ((16 * nt + c) << 6) + 16 * mt + 4 * g);
      st[mt][0] = bf2f((u16)(bp[0] & 0xffff)); st[mt][1] = bf2f((u16)(bp[0] >> 16));
      st[mt][2] = bf2f((u16)(bp[1] & 0xffff)); st[mt][3] = bf2f((u16)(bp[1] >> 16));
    }
#pragma unroll
    for (int mt = 0; mt < 4; ++mt)
      st[mt] = __builtin_amdgcn_mfma_f32_16x16x32_bf16(bkf[mt], aqf, st[mt], 0, 0, 0);
    float mx = st[0][0];
#pragma unroll
    for (int mt = 0; mt < 4; ++mt)
#pragma unroll
      for (int r = 0; r < 4; ++r) mx = fmaxf(mx, st[mt][r]);
    mx = fmaxf(mx, __shfl_xor(mx, 16));
    mx = fmaxf(mx, __shfl_xor(mx, 32));
    float sum = 0.f;
#pragma unroll
    for (int mt = 0; mt < 4; ++mt)
#pragma unroll
      for (int r = 0; r < 4; ++r) { float e = __expf(st[mt][r] - mx); st[mt][r] = e; sum += e; }
    sum += __shfl_xor(sum, 16);
    sum += __shfl_xor(sum, 32);
    float inv = 1.0f / sum;
#pragma unroll
    for (int mt = 0; mt < 4; ++mt) {
      Ppk[mt][nt][0] = pk2(st[mt][0] * inv, st[mt][1] * inv);
      Ppk[mt][nt][1] = pk2(st[mt][2] * inv, st[mt][3] * inv);
    }
  }

  // ---- PV in registers; paf built per-k2 (16 VGPR transient)
  f32x4 o[4][2] = {{{0,0,0,0},{0,0,0,0}},{{0,0,0,0},{0,0,0,0}},
                   {{0,0,0,0},{0,0,0,0}},{{0,0,0,0},{0,0,0,0}}};
#pragma unroll
  for (int k2 = 0; k2 < 2; ++k2) {
    bf16x8 paf4[4];
#pragma unroll
    for (int nt = 0; nt < 4; ++nt)
      paf4[nt] = frag_from(Ppk[2 * k2][nt][0], Ppk[2 * k2][nt][1],
                           Ppk[2 * k2 + 1][nt][0], Ppk[2 * k2 + 1][nt][1], s0, s1, hi);
#pragma unroll
    for (int nt = 0; nt < 4; ++nt) {
      o[nt][0] = __builtin_amdgcn_mfma_f32_16x16x32_bf16(paf4[nt], bvf[0][k2], o[nt][0], 0, 0, 0);
      o[nt][1] = __builtin_amdgcn_mfma_f32_16x16x32_bf16(paf4[nt], bvf[1][k2], o[nt][1], 0, 0, 0);
    }
  }

  // ---- y[token][32w+16dt+c] -> LDS (region freed at B2; disjoint per-wave cols)
#pragma unroll
  for (int nt = 0; nt < 4; ++nt)
#pragma unroll
    for (int dt = 0; dt < 2; ++dt)
#pragma unroll
      for (int r = 0; r < 4; ++r) {
        int n = 16 * nt + 4 * g + r, col = 32 * w + 16 * dt + c;
        *(u16*)(lds + n * XROW + col * 2) = f2bf(o[nt][dt][r]);
      }
  __syncthreads();   // B3: y complete

  // ---- proj: rt-half outer, ayh hoisted (LDS reads 64 -> 32); f32 scatter
  float* gout = out + (size_t)b * (NTOK * CDIM);
#pragma unroll
  for (int rth = 0; rth < 2; ++rth) {
    bf16x8 ayh[2][8];
#pragma unroll
    for (int rt2 = 0; rt2 < 2; ++rt2)
#pragma unroll
      for (int ks = 0; ks < 8; ++ks)
        ayh[rt2][ks] = *(const bf16x8*)(lds + (16 * (2 * rth + rt2) + c) * XROW + ks * 64 + g * 16);
#pragma unroll
    for (int ct = 0; ct < 2; ++ct) {
      const int colw = 32 * w + 16 * ct + c;
      const float badd = bf2f(ws[BPRJ_O + colw]);
      f32x4 acc2[2];
#pragma unroll
      for (int rt2 = 0; rt2 < 2; ++rt2)
#pragma unroll
        for (int r = 0; r < 4; ++r) acc2[rt2][r] = badd;
      const u16* wrow = ws + WPRJ_O + colw * CDIM;
#pragma unroll
      for (int ks = 0; ks < 8; ++ks) {
        bf16x8 wf = *(const bf16x8*)(wrow + ks * 32 + g * 8);
        acc2[0] = __builtin_amdgcn_mfma_f32_16x16x32_bf16(ayh[0][ks], wf, acc2[0], 0, 0, 0);
        acc2[1] = __builtin_amdgcn_mfma_f32_16x16x32_bf16(ayh[1][ks], wf, acc2[1], 0, 0, 0);
      }
#pragma unroll
      for (int rt2 = 0; rt2 < 2; ++rt2)
#pragma unroll
        for (int r = 0; r < 4; ++r) {
          int n = 16 * (2 * rth + rt2) + 4 * g + r;
          gout[n * CDIM + colw] = acc2[rt2][r];
        }
    }
  }
}

extern "C" void kernel_launch(void* const* d_in, const int* in_sizes, int n_in,
                              void* d_out, int out_size, void* d_ws, size_t ws_size,
                              hipStream_t stream) {
  (void)in_sizes; (void)n_in; (void)out_size; (void)ws_size;
  detect_dtype<<<dim3(1), dim3(256), 0, stream>>>((const u16*)d_in[0], (int*)d_ws);
  cvt_params<<<dim3(1156), dim3(256), 0, stream>>>(d_in[1], d_in[2], d_in[3], d_in[4],
                                                   d_in[5], d_ws);
  win_attn_fused<<<dim3(4096), dim3(512), 0, stream>>>(d_in[0], d_ws, (float*)d_out);
}